// Round 1
// baseline (1107.370 us; speedup 1.0000x reference)
//
#include <hip/hip_runtime.h>
#include <hip/hip_fp16.h>

#define B_ 2048
#define T_ 512
#define I_ 58   // input features
#define H_ 23   // hidden
#define G_ 69   // 3*H gates
#define GP_ 70  // padded gate row (even -> 4B-aligned half2 rows)

__device__ __forceinline__ float fast_rcp(float x) { return __builtin_amdgcn_rcpf(x); }
__device__ __forceinline__ float sigm(float x) { return fast_rcp(1.f + __expf(-x)); }
__device__ __forceinline__ float tanh_f(float x) {
    float e = __expf(-2.f * x);
    return (1.f - e) * fast_rcp(1.f + e);
}

// Kernel 1: x_proj[b][t][g] = dot(task_seq[b][t][:], W_ih[g][:]) + b_ih[g], stored fp16.
// One thread per (b,t). W_ih indices are wave-uniform -> scalar loads (K$-cached).
// Layout (B, T, GP_) so each row streams contiguously in t for the scan kernel.
__global__ __launch_bounds__(256) void k_xproj(
    const float* __restrict__ x, const float* __restrict__ Wih,
    const float* __restrict__ bih, __half* __restrict__ xg)
{
    int tid = blockIdx.x * 256 + threadIdx.x;      // tid = b*T + t (t fastest)
    const float2* xrow = (const float2*)(x + (size_t)tid * I_);  // 232B rows, 8B aligned
    float xv[I_];
#pragma unroll
    for (int p = 0; p < I_ / 2; ++p) {
        float2 v = xrow[p];
        xv[2 * p] = v.x;
        xv[2 * p + 1] = v.y;
    }
    __half2* orow = (__half2*)(xg + (size_t)tid * GP_);
#pragma unroll 1
    for (int gp = 0; gp < GP_ / 2; ++gp) {
        int g0 = 2 * gp, g1 = 2 * gp + 1;
        float a0 = bih[g0];
        float a1 = (g1 < G_) ? bih[g1] : 0.f;
        const float* w0 = Wih + (size_t)g0 * I_;
#pragma unroll
        for (int k = 0; k < I_; ++k) a0 = fmaf(w0[k], xv[k], a0);
        if (g1 < G_) {
            const float* w1 = Wih + (size_t)g1 * I_;
#pragma unroll
            for (int k = 0; k < I_; ++k) a1 = fmaf(w1[k], xv[k], a1);
        }
        __half2 hv;
        hv.x = __float2half(a0);
        hv.y = __float2half(a1);
        orow[gp] = hv;
    }
}

// Kernel 2: GRU scan. One wave handles 2 batch rows (half-wave each).
// Lane j (<23) owns hidden unit j: keeps W_hh rows j, j+23, j+46 in VGPRs,
// computes all three gate dots in-lane; old-h broadcast via __shfl (no LDS,
// no barriers -- rows never leave their wave). Next-step xg prefetched.
__global__ __launch_bounds__(64) void k_scan(
    const __half* __restrict__ xg, const float* __restrict__ Whh,
    const float* __restrict__ bhh, const float* __restrict__ pw,
    const float* __restrict__ pb, float* __restrict__ out)
{
    int lane = threadIdx.x;
    int j = lane & 31;
    int b = blockIdx.x * 2 + (lane >> 5);
    bool act = (j < H_);
    int jj = act ? j : 0;

    float w0[H_], w1[H_], w2[H_];
#pragma unroll
    for (int k = 0; k < H_; ++k) {
        w0[k] = Whh[jj * H_ + k];
        w1[k] = Whh[(jj + H_) * H_ + k];
        w2[k] = Whh[(jj + 2 * H_) * H_ + k];
    }
    float bh0 = bhh[jj], bh1 = bhh[jj + H_], bh2 = bhh[jj + 2 * H_];
    float pwj = pw[jj], pbj = pb[jj];

    const __half* row = xg + (size_t)b * T_ * GP_;
    float* arow = out + (size_t)b * T_ * H_;
    float* hid = out + (size_t)B_ * T_ * H_ + (size_t)b * H_;
    int rb = lane & 32;

    float h = 0.f;
    float xr = 0.f, xz = 0.f, xn = 0.f;
    if (act) {
        xr = __half2float(row[j]);
        xz = __half2float(row[j + H_]);
        xn = __half2float(row[j + 2 * H_]);
    }
#pragma unroll 1
    for (int t = 0; t < T_; ++t) {
        // prefetch t+1 (independent of the h chain)
        float nxr = 0.f, nxz = 0.f, nxn = 0.f;
        if (act && (t + 1 < T_)) {
            const __half* r2 = row + (size_t)(t + 1) * GP_;
            nxr = __half2float(r2[j]);
            nxz = __half2float(r2[j + H_]);
            nxn = __half2float(r2[j + 2 * H_]);
        }
        float hr = bh0, hz = bh1, hn = bh2;
#pragma unroll
        for (int k = 0; k < H_; ++k) {
            float hk = __shfl(h, rb + k, 64);
            hr = fmaf(w0[k], hk, hr);
            hz = fmaf(w1[k], hk, hz);
            hn = fmaf(w2[k], hk, hn);
        }
        float r = sigm(xr + hr);
        float z = sigm(xz + hz);
        float n = tanh_f(xn + r * hn);
        h = fmaf(z, h - n, n);   // (1-z)*n + z*h
        if (act) arow[(size_t)t * H_ + j] = fmaf(pwj, h, pbj);
        xr = nxr; xz = nxz; xn = nxn;
    }
    if (act) hid[j] = h;
}

extern "C" void kernel_launch(void* const* d_in, const int* in_sizes, int n_in,
                              void* d_out, int out_size, void* d_ws, size_t ws_size,
                              hipStream_t stream) {
    const float* task = (const float*)d_in[0];  // (B, T, I)
    const float* Wih  = (const float*)d_in[1];  // (3H, I)
    const float* Whh  = (const float*)d_in[2];  // (3H, H)
    const float* bih  = (const float*)d_in[3];  // (3H,)
    const float* bhh  = (const float*)d_in[4];  // (3H,)
    const float* pw   = (const float*)d_in[5];  // (H,)
    const float* pb   = (const float*)d_in[6];  // (H,)
    float* out = (float*)d_out;                 // action_pred (B,T,H) ++ hidden (1,B,H)
    __half* xgbuf = (__half*)d_ws;              // (B, T, GP_) fp16 = 146.8 MB

    k_xproj<<<(B_ * T_) / 256, 256, 0, stream>>>(task, Wih, bih, xgbuf);
    k_scan<<<B_ / 2, 64, 0, stream>>>(xgbuf, Whh, bhh, pw, pb, out);
}

// Round 2
// 807.001 us; speedup vs baseline: 1.3722x; 1.3722x over previous
//
#include <hip/hip_runtime.h>
#include <hip/hip_fp16.h>

#define B_ 2048
#define T_ 512
#define I_ 58   // input features
#define H_ 23   // hidden
#define G_ 69   // 3*H gates
#define WP_ 60  // W_ih row padded to 60 floats (240B -> b128-aligned LDS rows)

__device__ __forceinline__ float fast_rcp(float x) { return __builtin_amdgcn_rcpf(x); }
__device__ __forceinline__ float sigm(float x) { return fast_rcp(1.f + __expf(-x)); }
__device__ __forceinline__ float tanh_f(float x) {
    float e = __expf(-2.f * x);
    return (1.f - e) * fast_rcp(1.f + e);
}

// Kernel 1: x_proj, output TRANSPOSED as xg[b][g][t] (fp16), g in [0,69), t-major
// so the scan kernel can load 8 consecutive timesteps with one dwordx4.
// Block = (b, 256 t's). W_ih staged in LDS (rows padded to 60 floats, zeros in
// the pad so we can run a uniform 60-FMA loop). Per-thread x row in VGPRs.
// Transposed write goes through an LDS stage -> coalesced 8B global stores.
__global__ __launch_bounds__(256) void k_xproj(
    const float* __restrict__ x, const float* __restrict__ Wih,
    const float* __restrict__ bih, __half* __restrict__ xg)
{
    __shared__ float Wlds[G_ * WP_];      // 16560 B
    __shared__ __half stage[G_ * 256];    // 35328 B ; stage[g][t_local]

    int tid = threadIdx.x;
    int b = blockIdx.x >> 1;
    int t0 = (blockIdx.x & 1) << 8;

    // cooperative W_ih load with row re-pad 58 -> 60
    for (int idx = tid; idx < G_ * I_; idx += 256) {
        int g = idx / I_;
        int k = idx - g * I_;
        Wlds[g * WP_ + k] = Wih[idx];
    }
    for (int g = tid; g < G_; g += 256) {
        Wlds[g * WP_ + 58] = 0.f;
        Wlds[g * WP_ + 59] = 0.f;
    }

    // per-thread x row -> VGPRs (58 floats + 2 zero pads)
    const float2* xrow = (const float2*)(x + ((size_t)b * T_ + t0 + tid) * I_);
    float xv[WP_];
#pragma unroll
    for (int p = 0; p < I_ / 2; ++p) {
        float2 v = xrow[p];
        xv[2 * p] = v.x;
        xv[2 * p + 1] = v.y;
    }
    xv[58] = 0.f;
    xv[59] = 0.f;

    __syncthreads();

#pragma unroll 1
    for (int g = 0; g < G_; ++g) {
        float acc = bih[g];                 // uniform -> scalar load, K$ hit
        const float* wr = Wlds + g * WP_;
#pragma unroll
        for (int k = 0; k < WP_; ++k) acc = fmaf(wr[k], xv[k], acc);
        stage[g * 256 + tid] = __float2half(acc);
    }

    __syncthreads();

    // transposed write-out: per gate row, 256 halves = 512B contiguous.
    // flatten to (g, 8B-chunk) units: 69 * 64 = 4416 int2 chunks.
    const int2* s2 = (const int2*)stage;
#pragma unroll 1
    for (int idx = tid; idx < G_ * 64; idx += 256) {
        int g = idx >> 6;
        int c = idx & 63;
        __half* dst = xg + ((size_t)b * G_ + g) * T_ + t0;
        ((int2*)dst)[c] = s2[idx];
    }
}

// Kernel 2: GRU scan. One wave per 2 batch rows (half-wave each), lane j<23
// owns hidden unit j with W_hh rows in VGPRs; h broadcast via __shfl.
// x gates loaded 8 steps at a time (3 dwordx4), double-buffered one chunk
// ahead so load latency is fully off the dependent chain.
__global__ __launch_bounds__(64) void k_scan(
    const __half* __restrict__ xg, const float* __restrict__ Whh,
    const float* __restrict__ bhh, const float* __restrict__ pw,
    const float* __restrict__ pb, float* __restrict__ out)
{
    int lane = threadIdx.x;
    int j = lane & 31;
    int rb = lane & 32;
    int b = blockIdx.x * 2 + (lane >> 5);
    bool act = (j < H_);
    int jj = act ? j : 0;

    float w0[H_], w1[H_], w2[H_];
#pragma unroll
    for (int k = 0; k < H_; ++k) {
        w0[k] = Whh[jj * H_ + k];
        w1[k] = Whh[(jj + H_) * H_ + k];
        w2[k] = Whh[(jj + 2 * H_) * H_ + k];
    }
    float bh0 = bhh[jj], bh1 = bhh[jj + H_], bh2 = bhh[jj + 2 * H_];
    float pwj = pw[jj], pbj = pb[jj];

    const int4* pR = (const int4*)(xg + ((size_t)b * G_ + jj) * T_);
    const int4* pZ = (const int4*)(xg + ((size_t)b * G_ + jj + H_) * T_);
    const int4* pN = (const int4*)(xg + ((size_t)b * G_ + jj + 2 * H_) * T_);

    float* arow = out + (size_t)b * T_ * H_;

    int4 cR = pR[0], cZ = pZ[0], cN = pN[0];
    float h = 0.f;

#pragma unroll 1
    for (int c = 0; c < T_ / 8; ++c) {
        int4 nR, nZ, nN;
        if (c + 1 < T_ / 8) {       // prefetch next 8-step chunk
            nR = pR[c + 1];
            nZ = pZ[c + 1];
            nN = pN[c + 1];
        }
        const __half* hR = (const __half*)&cR;
        const __half* hZ = (const __half*)&cZ;
        const __half* hN = (const __half*)&cN;
#pragma unroll
        for (int s = 0; s < 8; ++s) {
            float xr = __half2float(hR[s]);
            float xz = __half2float(hZ[s]);
            float xn = __half2float(hN[s]);
            float hr = bh0, hz = bh1, hn = bh2;
#pragma unroll
            for (int k = 0; k < H_; ++k) {
                float hk = __shfl(h, rb + k, 64);
                hr = fmaf(w0[k], hk, hr);
                hz = fmaf(w1[k], hk, hz);
                hn = fmaf(w2[k], hk, hn);
            }
            float r = sigm(xr + hr);
            float z = sigm(xz + hz);
            float n = tanh_f(xn + r * hn);
            h = fmaf(z, h - n, n);   // (1-z)*n + z*h
            if (act) arow[(size_t)(c * 8 + s) * H_ + j] = fmaf(pwj, h, pbj);
        }
        cR = nR; cZ = nZ; cN = nN;
    }
    if (act) out[(size_t)B_ * T_ * H_ + (size_t)b * H_ + j] = h;
}

extern "C" void kernel_launch(void* const* d_in, const int* in_sizes, int n_in,
                              void* d_out, int out_size, void* d_ws, size_t ws_size,
                              hipStream_t stream) {
    const float* task = (const float*)d_in[0];  // (B, T, I)
    const float* Wih  = (const float*)d_in[1];  // (3H, I)
    const float* Whh  = (const float*)d_in[2];  // (3H, H)
    const float* bih  = (const float*)d_in[3];  // (3H,)
    const float* bhh  = (const float*)d_in[4];  // (3H,)
    const float* pw   = (const float*)d_in[5];  // (H,)
    const float* pb   = (const float*)d_in[6];  // (H,)
    float* out = (float*)d_out;                 // action_pred (B,T,H) ++ hidden (1,B,H)
    __half* xgbuf = (__half*)d_ws;              // transposed (B, G_, T) fp16 = 144.7 MB

    k_xproj<<<B_ * 2, 256, 0, stream>>>(task, Wih, bih, xgbuf);
    k_scan<<<B_ / 2, 64, 0, stream>>>(xgbuf, Whh, bhh, pw, pb, out);
}

// Round 3
// 718.306 us; speedup vs baseline: 1.5416x; 1.1235x over previous
//
#include <hip/hip_runtime.h>
#include <hip/hip_fp16.h>

#define B_ 2048
#define T_ 512
#define I_ 58   // input features
#define H_ 23   // hidden
#define G_ 69   // 3*H gates
#define TT_ 128 // t-tile per k_xproj block

// Constant-address-space pointer: forces wave-uniform W/b loads onto the
// scalar path (s_load + K$) instead of per-lane VMEM/LDS traffic.
typedef const __attribute__((address_space(4))) float* cfp4;
__device__ __forceinline__ cfp4 as_const(const float* p) {
    return (cfp4)(unsigned long long)p;
}

__device__ __forceinline__ float fast_rcp(float x) { return __builtin_amdgcn_rcpf(x); }
__device__ __forceinline__ float sigm(float x) { return fast_rcp(1.f + __expf(-x)); }
__device__ __forceinline__ float tanh_f(float x) {
    float e = __expf(-2.f * x);
    return (1.f - e) * fast_rcp(1.f + e);
}

// Kernel 1: x_proj -> xg[b][g][t] fp16 (transposed for the scan kernel).
// Block = 128 threads = 128 consecutive t's of one b.
//  - x staged global->LDS fully coalesced (29 float2 per thread), then each
//    thread pulls its own 58-float column into VGPRs.
//  - W_ih / b_ih read via scalar loads (address_space(4)): no LDS pipe, no VMEM.
//  - fp16 results staged in (the same) LDS, written out transposed & coalesced.
__global__ __launch_bounds__(128, 2) void k_xproj(
    const float* __restrict__ x, const float* __restrict__ Wih,
    const float* __restrict__ bih, __half* __restrict__ xg)
{
    __shared__ float xs[TT_ * I_];          // 29696 B; reused as fp16 out-stage
    __half* os = (__half*)xs;               // union; G_*TT_*2 = 17664 B fits

    int tid = threadIdx.x;
    int b = blockIdx.x >> 2;                // T_/TT_ = 4 tiles per b
    int t0 = (blockIdx.x & 3) * TT_;

    // coalesced stage: tile = TT_*I_*4 B = 3712 float2 -> 29 per thread
    const float2* src = (const float2*)(x + ((size_t)b * T_ + t0) * I_);
    float2* xs2 = (float2*)xs;
#pragma unroll
    for (int i = 0; i < 29; ++i) xs2[i * TT_ + tid] = src[i * TT_ + tid];
    __syncthreads();

    // own column -> VGPRs (row stride 58 floats: 2-way bank alias = free)
    float xv[I_];
    const float* col = xs + tid * I_;
#pragma unroll
    for (int k = 0; k < I_; ++k) xv[k] = col[k];
    __syncthreads();   // everyone done reading xs before os overwrites it

    cfp4 W4 = as_const(Wih);
    cfp4 b4 = as_const(bih);
#pragma unroll 3
    for (int g = 0; g < G_; ++g) {
        float a0 = b4[g], a1 = 0.f, a2 = 0.f, a3 = 0.f;
        cfp4 wr = W4 + g * I_;
#pragma unroll
        for (int k = 0; k < 56; k += 4) {
            a0 = fmaf(wr[k + 0], xv[k + 0], a0);
            a1 = fmaf(wr[k + 1], xv[k + 1], a1);
            a2 = fmaf(wr[k + 2], xv[k + 2], a2);
            a3 = fmaf(wr[k + 3], xv[k + 3], a3);
        }
        a0 = fmaf(wr[56], xv[56], a0);
        a1 = fmaf(wr[57], xv[57], a1);
        os[g * TT_ + tid] = __float2half((a0 + a2) + (a1 + a3));
    }
    __syncthreads();

    // transposed write-out: per gate 128 halves = 256 B = 32 int2 chunks
    const int2* s2 = (const int2*)os;
#pragma unroll 1
    for (int idx = tid; idx < G_ * (TT_ / 4); idx += 128) {
        int g = idx >> 5;
        int c = idx & 31;
        __half* dst = xg + ((size_t)b * G_ + g) * T_ + t0;
        ((int2*)dst)[c] = s2[idx];
    }
}

// Kernel 2: GRU scan. One wave per 2 batch rows (half-wave each); lane j<23
// owns hidden unit j with its 3 W_hh rows in VGPRs (launch_bounds(64,1) so
// the compiler gets the full register budget -- round-2's (64) default parked
// them in AGPRs). All 23 h-broadcasts issue as one ds_bpermute batch (one
// exposed lgkmcnt wait per step, not 23), dots use 2-way split accumulators.
__global__ __launch_bounds__(64, 1) void k_scan(
    const __half* __restrict__ xg, const float* __restrict__ Whh,
    const float* __restrict__ bhh, const float* __restrict__ pw,
    const float* __restrict__ pb, float* __restrict__ out)
{
    int lane = threadIdx.x;
    int j = lane & 31;
    int rb = lane & 32;
    int b = blockIdx.x * 2 + (lane >> 5);
    bool act = (j < H_);
    int jj = act ? j : 0;

    float w0[H_], w1[H_], w2[H_];
#pragma unroll
    for (int k = 0; k < H_; ++k) {
        w0[k] = Whh[jj * H_ + k];
        w1[k] = Whh[(jj + H_) * H_ + k];
        w2[k] = Whh[(jj + 2 * H_) * H_ + k];
    }
    float bh0 = bhh[jj], bh1 = bhh[jj + H_], bh2 = bhh[jj + 2 * H_];
    float pwj = pw[jj], pbj = pb[jj];

    const int4* pR = (const int4*)(xg + ((size_t)b * G_ + jj) * T_);
    const int4* pZ = (const int4*)(xg + ((size_t)b * G_ + jj + H_) * T_);
    const int4* pN = (const int4*)(xg + ((size_t)b * G_ + jj + 2 * H_) * T_);

    float* arow = out + (size_t)b * T_ * H_;

    int4 cR = pR[0], cZ = pZ[0], cN = pN[0];
    float h = 0.f;

#pragma unroll 1
    for (int c = 0; c < T_ / 8; ++c) {
        int4 nR = {0, 0, 0, 0}, nZ = {0, 0, 0, 0}, nN = {0, 0, 0, 0};
        if (c + 1 < T_ / 8) {       // prefetch next 8-step chunk
            nR = pR[c + 1];
            nZ = pZ[c + 1];
            nN = pN[c + 1];
        }
        const __half* hR = (const __half*)&cR;
        const __half* hZ = (const __half*)&cZ;
        const __half* hN = (const __half*)&cN;
#pragma unroll
        for (int s = 0; s < 8; ++s) {
            // batch ALL broadcasts first: one exposed LDS latency per step
            float hb[H_];
#pragma unroll
            for (int k = 0; k < H_; ++k) hb[k] = __shfl(h, rb + k, 64);

            float xr = __half2float(hR[s]);
            float xz = __half2float(hZ[s]);
            float xn = __half2float(hN[s]);

            float rA = bh0, rB = 0.f, zA = bh1, zB = 0.f, nA = bh2, nB = 0.f;
#pragma unroll
            for (int k = 0; k < 12; ++k) {
                rA = fmaf(w0[k], hb[k], rA);
                zA = fmaf(w1[k], hb[k], zA);
                nA = fmaf(w2[k], hb[k], nA);
            }
#pragma unroll
            for (int k = 12; k < H_; ++k) {
                rB = fmaf(w0[k], hb[k], rB);
                zB = fmaf(w1[k], hb[k], zB);
                nB = fmaf(w2[k], hb[k], nB);
            }
            float r = sigm(xr + rA + rB);
            float z = sigm(xz + zA + zB);
            float n = tanh_f(xn + r * (nA + nB));
            h = fmaf(z, h - n, n);   // (1-z)*n + z*h
            if (act) arow[(size_t)(c * 8 + s) * H_ + j] = fmaf(pwj, h, pbj);
        }
        cR = nR; cZ = nZ; cN = nN;
    }
    if (act) out[(size_t)B_ * T_ * H_ + (size_t)b * H_ + j] = h;
}

extern "C" void kernel_launch(void* const* d_in, const int* in_sizes, int n_in,
                              void* d_out, int out_size, void* d_ws, size_t ws_size,
                              hipStream_t stream) {
    const float* task = (const float*)d_in[0];  // (B, T, I)
    const float* Wih  = (const float*)d_in[1];  // (3H, I)
    const float* Whh  = (const float*)d_in[2];  // (3H, H)
    const float* bih  = (const float*)d_in[3];  // (3H,)
    const float* bhh  = (const float*)d_in[4];  // (3H,)
    const float* pw   = (const float*)d_in[5];  // (H,)
    const float* pb   = (const float*)d_in[6];  // (H,)
    float* out = (float*)d_out;                 // action_pred (B,T,H) ++ hidden (1,B,H)
    __half* xgbuf = (__half*)d_ws;              // transposed (B, G_, T) fp16 = 144.7 MB

    k_xproj<<<B_ * 4, TT_, 0, stream>>>(task, Wih, bih, xgbuf);
    k_scan<<<B_ / 2, 64, 0, stream>>>(xgbuf, Whh, bhh, pw, pb, out);
}